// Round 6
// baseline (27.873 us; speedup 1.0000x reference)
//
#include <hip/hip_runtime.h>

// Bidirectional Chamfer distance, fp32, shapes (16, 2048, 3). Single kernel.
//
// Grid: 256 blocks = dir(2) x batch(16) x query-chunk(8), 1024 thr = 16 waves
// (1 block/CU, 4 waves/SIMD). Block owns 256 queries (Q=4/lane in registers);
// wave w scans targets [w*128, (w+1)*128) from a 32 KB LDS float4 tile
// (x,y,z,|t|^2), broadcast ds_read_b128, software-pipelined (next quad
// prefetched into regs while current quad is in the FMA/min3 body).
//
// Math: d2 = |p|^2 + |t|^2 - 2 p.t. Per lane q = -2p;
// d2' = fma(qz,tz, fma(qy,ty, fma(qx,tx, tw))); two targets fold into one
// v_min3_f32. |p|^2 added after the scan (commutes with min).
//
// Reduction fused via last-block pattern: each block release-stores one
// partial to d_ws and bumps a counter (256 atomics, distinct lines); the
// last block acquire-loads the 256 partials and writes out[0] directly.
// Counter is zeroed each call by a 4-byte hipMemsetAsync (ws is poisoned
// once, never re-poisoned between replays).

#define NPTS  2048
#define BATCH 16
#define NBLK  256

__global__ __launch_bounds__(1024) void chamfer_kernel(
    const float* __restrict__ pred,
    const float* __restrict__ tgt,
    float* __restrict__ partial,
    unsigned int* __restrict__ counter,
    float* __restrict__ out)
{
    const int bid = blockIdx.x;
    const int dir = bid >> 7;          // 0: pred->tgt, 1: tgt->pred
    const int b   = (bid >> 3) & 15;   // batch
    const int qc  = bid & 7;           // query chunk of 256

    const int tid  = threadIdx.x;
    const int lane = tid & 63;
    const int w    = tid >> 6;         // wave 0..15

    const float* __restrict__ P = dir ? tgt  : pred;  // query cloud
    const float* __restrict__ T = dir ? pred : tgt;   // other cloud
    const float* Pb = P + (size_t)b * NPTS * 3;
    const float* Tb = T + (size_t)b * NPTS * 3;

    __shared__ float4 tile[NPTS];      // 32 KB: x, y, z, |t|^2
    __shared__ float  smin[16][256];   // 16 KB: per-wave partial mins
    __shared__ float  spart[4];
    __shared__ int    slast;

    // --- Stage the full target cloud into LDS (2 points per thread) ---
    #pragma unroll
    for (int k = 0; k < 2; ++k) {
        const int idx = tid + k * 1024;
        const float x = Tb[idx * 3 + 0];
        const float y = Tb[idx * 3 + 1];
        const float z = Tb[idx * 3 + 2];
        tile[idx] = make_float4(x, y, z, x * x + y * y + z * z);
    }

    // --- Load 4 query points per lane; fold -2 into the query ---
    float qx[4], qy[4], qz[4], pp[4], m0[4], m1[4];
    #pragma unroll
    for (int q = 0; q < 4; ++q) {
        const int qi = qc * 256 + q * 64 + lane;
        const float x = Pb[qi * 3 + 0];
        const float y = Pb[qi * 3 + 1];
        const float z = Pb[qi * 3 + 2];
        qx[q] = -2.0f * x;
        qy[q] = -2.0f * y;
        qz[q] = -2.0f * z;
        pp[q] = x * x + y * y + z * z;
        m0[q] = 3.4e38f;
        m1[q] = 3.4e38f;
    }

    __syncthreads();

    // --- Software-pipelined scan of this wave's 128-target slice ---
    const int base = w * 128;
    float4 ta = tile[base + 0];
    float4 tb = tile[base + 1];
    float4 tc = tile[base + 2];
    float4 td = tile[base + 3];

    #pragma unroll 2
    for (int j = 0; j < 128; j += 4) {
        const int nj = base + ((j + 4) & 127);   // wrap: last iter re-reads 0..3
        const float4 na = tile[nj + 0];
        const float4 nb = tile[nj + 1];
        const float4 nc = tile[nj + 2];
        const float4 nd = tile[nj + 3];
        #pragma unroll
        for (int q = 0; q < 4; ++q) {
            const float da = fmaf(qz[q], ta.z, fmaf(qy[q], ta.y, fmaf(qx[q], ta.x, ta.w)));
            const float db = fmaf(qz[q], tb.z, fmaf(qy[q], tb.y, fmaf(qx[q], tb.x, tb.w)));
            const float dc = fmaf(qz[q], tc.z, fmaf(qy[q], tc.y, fmaf(qx[q], tc.x, tc.w)));
            const float dd = fmaf(qz[q], td.z, fmaf(qy[q], td.y, fmaf(qx[q], td.x, td.w)));
            m0[q] = fminf(fminf(m0[q], da), db);   // -> v_min3_f32
            m1[q] = fminf(fminf(m1[q], dc), dd);   // -> v_min3_f32
        }
        ta = na; tb = nb; tc = nc; td = nd;
    }

    // --- Cross-wave min combine (add |p|^2 here: commutes with min) ---
    #pragma unroll
    for (int q = 0; q < 4; ++q)
        smin[w][q * 64 + lane] = fminf(m0[q], m1[q]) + pp[q];
    __syncthreads();

    // --- Block partial: min across 16 waves, sum across 256 queries ---
    if (tid < 256) {
        float v = smin[0][tid];
        #pragma unroll
        for (int ww = 1; ww < 16; ++ww)
            v = fminf(v, smin[ww][tid]);
        #pragma unroll
        for (int off = 32; off > 0; off >>= 1)
            v += __shfl_down(v, off);
        if (lane == 0)
            spart[w] = v;              // w in 0..3 here
    }
    __syncthreads();

    if (tid == 0) {
        const float s = spart[0] + spart[1] + spart[2] + spart[3];
        __hip_atomic_store(&partial[bid], s, __ATOMIC_RELEASE,
                           __HIP_MEMORY_SCOPE_AGENT);
        const unsigned int old = __hip_atomic_fetch_add(
            counter, 1u, __ATOMIC_ACQ_REL, __HIP_MEMORY_SCOPE_AGENT);
        slast = (old == NBLK - 1);
    }
    __syncthreads();

    // --- Last block to finish sums the 256 partials -> out[0] ---
    if (slast) {
        if (tid < 256) {
            float v = __hip_atomic_load(&partial[tid], __ATOMIC_RELAXED,
                                        __HIP_MEMORY_SCOPE_AGENT);
            #pragma unroll
            for (int off = 32; off > 0; off >>= 1)
                v += __shfl_down(v, off);
            if (lane == 0)
                spart[w] = v;
        }
        __syncthreads();
        if (tid == 0)
            out[0] = (spart[0] + spart[1] + spart[2] + spart[3])
                     * (1.0f / (float)(BATCH * NPTS));
    }
}

extern "C" void kernel_launch(void* const* d_in, const int* in_sizes, int n_in,
                              void* d_out, int out_size, void* d_ws, size_t ws_size,
                              hipStream_t stream)
{
    const float* pred = (const float*)d_in[0];
    const float* tgt  = (const float*)d_in[1];
    float* out = (float*)d_out;
    float* partial = (float*)d_ws;                       // 256 floats
    unsigned int* counter = (unsigned int*)((char*)d_ws + NBLK * sizeof(float));

    // Counter must start at 0 every call (ws poisoned 0xAA once, never
    // re-poisoned between replays; partial[] is fully rewritten each call).
    hipMemsetAsync(counter, 0, sizeof(unsigned int), stream);

    chamfer_kernel<<<dim3(NBLK), dim3(1024), 0, stream>>>(pred, tgt, partial,
                                                          counter, out);
}

// Round 7
// 22.581 us; speedup vs baseline: 1.2344x; 1.2344x over previous
//
#include <hip/hip_runtime.h>

// Bidirectional Chamfer distance, fp32, shapes (16, 2048, 3).
//
// R7: revert R6's fused reduction (agent-scope acq/rel cache ops regressed)
// and SW pipeline. Keep R5's two-kernel shape; change ONLY the partition to
// halve per-CU LDS-pipe traffic (the inferred limiter):
//   - 256 blocks = dir(2) x batch(16) x query-chunk(4) x target-half(2)
//   - Block owns 512 queries (Q=8/lane) and scans 1024 targets (its half);
//     wave w scans 64 targets -> 1024 broadcast ds_read_b128 per block
//     (was 2048), while VALU/pair stays 3.5 (3 fma + half a v_min3).
//   - Per-block output: 512 per-query mins (true d2, >= 0) -> d_ws.
//   - reduce_kernel (1 block x 1024 thr): for each query, min over the two
//     target-half blocks, then global sum -> out[0]. 512 KB L2-resident.
//
// Math: d2 = |p|^2 + |t|^2 - 2 p.t. Per lane q = -2p;
// d2' = fma(qz,tz, fma(qy,ty, fma(qx,tx, tw))); two targets fold into one
// v_min3_f32. |p|^2 added at smin-write (commutes with min).

#define NPTS  2048
#define BATCH 16
#define NBLK  256
#define QPB   512            // queries per block
#define TPB   1024           // targets per block (half cloud)

__global__ __launch_bounds__(1024) void chamfer_kernel(
    const float* __restrict__ pred,
    const float* __restrict__ tgt,
    float* __restrict__ partial)     // [NBLK][QPB]
{
    const int bid = blockIdx.x;
    const int dir = bid >> 7;          // 0: pred->tgt, 1: tgt->pred
    const int b   = (bid >> 3) & 15;   // batch
    const int qc  = (bid >> 1) & 3;    // query chunk of 512
    const int th  = bid & 1;           // target half

    const int tid  = threadIdx.x;
    const int lane = tid & 63;
    const int w    = tid >> 6;         // wave 0..15

    const float* __restrict__ P = dir ? tgt  : pred;  // query cloud
    const float* __restrict__ T = dir ? pred : tgt;   // other cloud
    const float* Pb = P + (size_t)b * NPTS * 3;
    const float* Tb = T + (size_t)b * NPTS * 3 + (size_t)th * TPB * 3;

    __shared__ float4 tile[TPB];       // 16 KB: x, y, z, |t|^2
    __shared__ float  smin[16][QPB];   // 32 KB: per-wave partial mins

    // --- Stage this block's 1024-target half into LDS (1 pt/thread) ---
    {
        const float x = Tb[tid * 3 + 0];
        const float y = Tb[tid * 3 + 1];
        const float z = Tb[tid * 3 + 2];
        tile[tid] = make_float4(x, y, z, x * x + y * y + z * z);
    }

    // --- Load 8 query points per lane; fold -2 into the query ---
    float qx[8], qy[8], qz[8], pp[8], m0[8], m1[8];
    #pragma unroll
    for (int q = 0; q < 8; ++q) {
        const int qi = qc * QPB + q * 64 + lane;
        const float x = Pb[qi * 3 + 0];
        const float y = Pb[qi * 3 + 1];
        const float z = Pb[qi * 3 + 2];
        qx[q] = -2.0f * x;
        qy[q] = -2.0f * y;
        qz[q] = -2.0f * z;
        pp[q] = x * x + y * y + z * z;
        m0[q] = 3.4e38f;
        m1[q] = 3.4e38f;
    }

    __syncthreads();

    // --- Scan this wave's 64-target slice (broadcast ds_read_b128) ---
    const int base = w * 64;
    #pragma unroll 2
    for (int j = 0; j < 64; j += 4) {
        const float4 ta = tile[base + j + 0];
        const float4 tb = tile[base + j + 1];
        const float4 tc = tile[base + j + 2];
        const float4 td = tile[base + j + 3];
        #pragma unroll
        for (int q = 0; q < 8; ++q) {
            const float da = fmaf(qz[q], ta.z, fmaf(qy[q], ta.y, fmaf(qx[q], ta.x, ta.w)));
            const float db = fmaf(qz[q], tb.z, fmaf(qy[q], tb.y, fmaf(qx[q], tb.x, tb.w)));
            const float dc = fmaf(qz[q], tc.z, fmaf(qy[q], tc.y, fmaf(qx[q], tc.x, tc.w)));
            const float dd = fmaf(qz[q], td.z, fmaf(qy[q], td.y, fmaf(qx[q], td.x, td.w)));
            m0[q] = fminf(fminf(m0[q], da), db);   // -> v_min3_f32
            m1[q] = fminf(fminf(m1[q], dc), dd);   // -> v_min3_f32
        }
    }

    // --- Cross-wave min combine (add |p|^2 here: commutes with min) ---
    #pragma unroll
    for (int q = 0; q < 8; ++q)
        smin[w][q * 64 + lane] = fminf(m0[q], m1[q]) + pp[q];
    __syncthreads();

    // --- Per-query min over 16 waves; one contiguous 512-float store ---
    if (tid < QPB) {
        float v = smin[0][tid];
        #pragma unroll
        for (int ww = 1; ww < 16; ++ww)
            v = fminf(v, smin[ww][tid]);
        partial[bid * QPB + tid] = v;   // true d2 >= 0
    }
}

// One block, 1024 threads: out[0] = sum over 128 groups x 512 queries of
// min(half0, half1), scaled by 1/(BATCH*NPTS). 512 KB, L2/L3-resident.
__global__ __launch_bounds__(1024) void reduce_kernel(
    const float* __restrict__ partial,
    float* __restrict__ out)
{
    const int tid  = threadIdx.x;
    const int lane = tid & 63;
    const int w    = tid >> 6;
    __shared__ float s[16];

    const float4* P4 = (const float4*)partial;
    float acc = 0.0f;

    // 128 groups x 128 float4-pairs = 16384 pairs; 16 iters x 1024 threads.
    #pragma unroll 4
    for (int i = 0; i < 16; ++i) {
        const int pairIdx = i * 1024 + tid;
        const int g  = pairIdx >> 7;          // group (dir,b,qc)
        const int q4 = pairIdx & 127;         // float4 index within 512 queries
        const float4 va = P4[g * 256 + q4];          // half 0 (th=0 block)
        const float4 vb = P4[g * 256 + 128 + q4];    // half 1 (th=1 block)
        acc += fminf(va.x, vb.x) + fminf(va.y, vb.y)
             + fminf(va.z, vb.z) + fminf(va.w, vb.w);
    }

    #pragma unroll
    for (int off = 32; off > 0; off >>= 1)
        acc += __shfl_down(acc, off);
    if (lane == 0) s[w] = acc;
    __syncthreads();

    if (tid == 0) {
        float t = 0.0f;
        #pragma unroll
        for (int ww = 0; ww < 16; ++ww) t += s[ww];
        out[0] = t * (1.0f / (float)(BATCH * NPTS));
    }
}

extern "C" void kernel_launch(void* const* d_in, const int* in_sizes, int n_in,
                              void* d_out, int out_size, void* d_ws, size_t ws_size,
                              hipStream_t stream)
{
    const float* pred = (const float*)d_in[0];
    const float* tgt  = (const float*)d_in[1];
    float* out = (float*)d_out;
    float* partial = (float*)d_ws;     // 256 * 512 floats = 512 KB, fully
                                       // rewritten each call (no init needed)

    chamfer_kernel<<<dim3(NBLK), dim3(1024), 0, stream>>>(pred, tgt, partial);
    reduce_kernel<<<dim3(1), dim3(1024), 0, stream>>>(partial, out);
}

// Round 8
// 19.914 us; speedup vs baseline: 1.3997x; 1.1339x over previous
//
#include <hip/hip_runtime.h>

// Bidirectional Chamfer distance, fp32, shapes (16, 2048, 3).
//
// R8: packed-fp32 inner loop (v_pk_fma_f32, 2 targets per instruction).
//  - chamfer: 256 blocks = dir(2) x batch(16) x query-chunk(4) x half(2),
//    1024 thr = 16 waves. Block owns 512 queries (Q=8/lane, replicated into
//    both packed halves at setup) and scans its 1024-target half from LDS,
//    stored pairwise: t2a[jp]={x0,x1,y0,y1}, t2b[jp]={z0,z1,w0,w1} -> per
//    pair 2x ds_read_b128 (same LDS instr count per target as R5/R7).
//    Per pair per query: 3 pk_fma + 1 v_min3 = 4 instr / 2 targets
//    (vs 7 scalar) -> VALU ~1.75x fewer instructions.
//  - reduce1: 128 blocks, one (dir,b,qc) group each: sum over 512 queries of
//    min(half0, half1) -> gsum[128]. Parallel, 4 KB per block.
//  - reduce2: 1 block, 128 threads: sum gsum -> out[0] * 1/(16*2048).
// No atomics, no memset; every ws byte consumed is rewritten each call.
//
// Math: d2 = |p|^2 + |t|^2 - 2 p.t; q=-2p folded, |p|^2 added at smin-write.

typedef float f2 __attribute__((ext_vector_type(2)));
typedef float f4 __attribute__((ext_vector_type(4)));

#define NPTS  2048
#define BATCH 16
#define NBLK  256
#define QPB   512            // queries per block
#define TPB   1024           // targets per block (half cloud)
#define NGRP  128            // (dir, batch, query-chunk) groups

static __device__ __forceinline__ f2 pk_fma(f2 a, f2 b, f2 c) {
    f2 d;
    asm("v_pk_fma_f32 %0, %1, %2, %3" : "=v"(d) : "v"(a), "v"(b), "v"(c));
    return d;
}

__global__ __launch_bounds__(1024) void chamfer_kernel(
    const float* __restrict__ pred,
    const float* __restrict__ tgt,
    float* __restrict__ partial)     // [NBLK][QPB]
{
    const int bid = blockIdx.x;
    const int dir = bid >> 7;          // 0: pred->tgt, 1: tgt->pred
    const int b   = (bid >> 3) & 15;   // batch
    const int qc  = (bid >> 1) & 3;    // query chunk of 512
    const int th  = bid & 1;           // target half

    const int tid  = threadIdx.x;
    const int lane = tid & 63;
    const int w    = tid >> 6;         // wave 0..15

    const float* __restrict__ P = dir ? tgt  : pred;  // query cloud
    const float* __restrict__ T = dir ? pred : tgt;   // other cloud
    const float* Pb = P + (size_t)b * NPTS * 3;
    const float* Tb = T + (size_t)b * NPTS * 3 + (size_t)th * TPB * 3;

    __shared__ f4    t2a[TPB / 2];     // 8 KB: {x0,x1,y0,y1} per pair
    __shared__ f4    t2b[TPB / 2];     // 8 KB: {z0,z1,w0,w1} per pair
    __shared__ float smin[16][QPB];    // 32 KB: per-wave partial mins

    // --- Stage 512 target-pairs into LDS (one pair per thread < 512) ---
    if (tid < TPB / 2) {
        const int jp = tid;
        const float x0 = Tb[(2 * jp) * 3 + 0];
        const float y0 = Tb[(2 * jp) * 3 + 1];
        const float z0 = Tb[(2 * jp) * 3 + 2];
        const float x1 = Tb[(2 * jp + 1) * 3 + 0];
        const float y1 = Tb[(2 * jp + 1) * 3 + 1];
        const float z1 = Tb[(2 * jp + 1) * 3 + 2];
        f4 A; A.x = x0; A.y = x1; A.z = y0; A.w = y1;
        f4 B; B.x = z0; B.y = z1;
        B.z = x0 * x0 + y0 * y0 + z0 * z0;
        B.w = x1 * x1 + y1 * y1 + z1 * z1;
        t2a[jp] = A;
        t2b[jp] = B;
    }

    // --- Load 8 queries/lane; fold -2; replicate into packed halves ---
    f2 qx2[8], qy2[8], qz2[8];
    float pp[8], m0[8], m1[8];
    #pragma unroll
    for (int q = 0; q < 8; ++q) {
        const int qi = qc * QPB + q * 64 + lane;
        const float x = Pb[qi * 3 + 0];
        const float y = Pb[qi * 3 + 1];
        const float z = Pb[qi * 3 + 2];
        const float ax = -2.0f * x, ay = -2.0f * y, az = -2.0f * z;
        qx2[q].x = ax; qx2[q].y = ax;
        qy2[q].x = ay; qy2[q].y = ay;
        qz2[q].x = az; qz2[q].y = az;
        pp[q] = x * x + y * y + z * z;
        m0[q] = 3.4e38f;
        m1[q] = 3.4e38f;
    }

    __syncthreads();

    // --- Scan this wave's 32 target-pairs (64 targets) ---
    const int base = w * 32;
    #pragma unroll 4
    for (int jp = 0; jp < 32; jp += 2) {
        const f4 A0 = t2a[base + jp + 0];
        const f4 B0 = t2b[base + jp + 0];
        const f4 A1 = t2a[base + jp + 1];
        const f4 B1 = t2b[base + jp + 1];
        #pragma unroll
        for (int q = 0; q < 8; ++q) {
            f2 s0 = pk_fma(qx2[q], A0.lo, B0.hi);   // x*qx + |t|^2
            s0 = pk_fma(qy2[q], A0.hi, s0);
            s0 = pk_fma(qz2[q], B0.lo, s0);
            m0[q] = fminf(fminf(m0[q], s0.x), s0.y);   // v_min3_f32
            f2 s1 = pk_fma(qx2[q], A1.lo, B1.hi);
            s1 = pk_fma(qy2[q], A1.hi, s1);
            s1 = pk_fma(qz2[q], B1.lo, s1);
            m1[q] = fminf(fminf(m1[q], s1.x), s1.y);   // v_min3_f32
        }
    }

    // --- Cross-wave min combine (add |p|^2 here: commutes with min) ---
    #pragma unroll
    for (int q = 0; q < 8; ++q)
        smin[w][q * 64 + lane] = fminf(m0[q], m1[q]) + pp[q];
    __syncthreads();

    // --- Per-query min over 16 waves; contiguous 512-float store ---
    if (tid < QPB) {
        float v = smin[0][tid];
        #pragma unroll
        for (int ww = 1; ww < 16; ++ww)
            v = fminf(v, smin[ww][tid]);
        partial[bid * QPB + tid] = v;   // true d2 >= 0
    }
}

// reduce1: one block per (dir,b,qc) group: sum over 512 queries of
// min(half0, half1) -> gsum[g]. 256 threads, 2 queries each.
__global__ __launch_bounds__(256) void reduce1_kernel(
    const float* __restrict__ partial,
    float* __restrict__ gsum)
{
    const int g    = blockIdx.x;
    const int tid  = threadIdx.x;
    const int lane = tid & 63;
    const int w    = tid >> 6;
    __shared__ float s[4];

    const float* p0 = partial + (size_t)(2 * g) * QPB;
    const float* p1 = partial + (size_t)(2 * g + 1) * QPB;

    float acc = fminf(p0[tid], p1[tid]) + fminf(p0[tid + 256], p1[tid + 256]);
    #pragma unroll
    for (int off = 32; off > 0; off >>= 1)
        acc += __shfl_down(acc, off);
    if (lane == 0) s[w] = acc;
    __syncthreads();
    if (tid == 0)
        gsum[g] = s[0] + s[1] + s[2] + s[3];
}

// reduce2: single block sums the 128 group sums -> out[0].
__global__ __launch_bounds__(128) void reduce2_kernel(
    const float* __restrict__ gsum,
    float* __restrict__ out)
{
    const int tid  = threadIdx.x;
    const int lane = tid & 63;
    __shared__ float s[2];

    float v = gsum[tid];
    #pragma unroll
    for (int off = 32; off > 0; off >>= 1)
        v += __shfl_down(v, off);
    if (lane == 0) s[tid >> 6] = v;
    __syncthreads();
    if (tid == 0)
        out[0] = (s[0] + s[1]) * (1.0f / (float)(BATCH * NPTS));
}

extern "C" void kernel_launch(void* const* d_in, const int* in_sizes, int n_in,
                              void* d_out, int out_size, void* d_ws, size_t ws_size,
                              hipStream_t stream)
{
    const float* pred = (const float*)d_in[0];
    const float* tgt  = (const float*)d_in[1];
    float* out = (float*)d_out;
    float* partial = (float*)d_ws;                            // 512 KB
    float* gsum    = (float*)d_ws + (size_t)NBLK * QPB;       // 128 floats

    chamfer_kernel<<<dim3(NBLK), dim3(1024), 0, stream>>>(pred, tgt, partial);
    reduce1_kernel<<<dim3(NGRP), dim3(256), 0, stream>>>(partial, gsum);
    reduce2_kernel<<<dim3(1), dim3(128), 0, stream>>>(gsum, out);
}